// Round 9
// baseline (483.334 us; speedup 1.0000x reference)
//
#include <hip/hip_runtime.h>
#include <cstdint>
#include <cstddef>

#define BATCH 64
#define CH 3
#define HH 256
#define WW 256
#define NBINS 256
#define TILE 32
#define HALO 5
#define HPAD 36                /* hA row stride: pads b128-store bank pattern */
#define NPB (CH*HH*WW)         /* 196608 elements per batch item */
#define EPX (NPB/8)            /* 24576 pixels per eighth-batch-item */

__device__ __forceinline__ float block_reduce_256(float v, float* buf4) {
    #pragma unroll
    for (int o = 32; o > 0; o >>= 1) v += __shfl_down(v, o, 64);
    __syncthreads();
    int lane = threadIdx.x & 63;
    int wid  = threadIdx.x >> 6;
    if (lane == 0) buf4[wid] = v;
    __syncthreads();
    return buf4[0] + buf4[1] + buf4[2] + buf4[3];
}

__device__ __forceinline__ float block_reduce_1024(float v, float* buf16) {
    #pragma unroll
    for (int o = 32; o > 0; o >>= 1) v += __shfl_down(v, o, 64);
    __syncthreads();
    int lane = threadIdx.x & 63;
    int wid  = threadIdx.x >> 6;
    if (lane == 0) buf16[wid] = v;
    __syncthreads();
    float s = 0.0f;
    #pragma unroll
    for (int i = 0; i < 16; i++) s += buf16[i];
    return s;
}

// Separable 11x11 gaussian conv -> per-pixel SSIM (round-7 structure, 88 us).
// Block (0,0,0) also zeroes done_cnt (replaces a memset dispatch).
__global__ __launch_bounds__(256) void ssim_conv_kernel(
    const float* __restrict__ x, const float* __restrict__ y,
    const float* __restrict__ win,
    float* __restrict__ ssim_partials,
    unsigned int* __restrict__ done_cnt)
{
    __shared__ float hA[5][42][HPAD];   // 30.2 KB
    __shared__ float g[16];
    __shared__ float rbuf[4];

    const int tid = threadIdx.x;
    const int tx = blockIdx.x, ty = blockIdx.y, z = blockIdx.z;  // z = b*3 + c
    const float* xi = x + (size_t)z * (HH * WW);
    const float* yi = y + (size_t)z * (HH * WW);

    if (tx == 0 && ty == 0 && z == 0 && tid < BATCH) done_cnt[tid] = 0;

    if (tid < 11) {
        // window = outer(g,g); recover g: g[i] = w2[5][i] / sqrt(w2[5][5])
        float g5 = sqrtf(win[5*11 + 5]);
        g[tid] = win[5*11 + tid] / g5;
    }
    __syncthreads();

    // ---- Horizontal pass: 42 rows x 4 strips of 8 -> 168 strips, one pass ----
    if (tid < 42 * 4) {
        int r = tid >> 2;
        int c0 = (tid & 3) * 8;
        int gr = ty * TILE - HALO + r;
        int gw = tx * TILE + c0 - HALO;       // gw % 8 == 3
        float xw[18], yw[18];
        bool rowok = (gr >= 0 && gr < HH);
        if (rowok) {
            const float* xr = xi + gr * WW;
            const float* yr = yi + gr * WW;
            int ga = gw - 3;                  // 16B-aligned
            if (ga >= 0 && ga + 24 <= WW) {
                float t0[24], t1[24];
                const float4* px4 = (const float4*)(xr + ga);
                const float4* py4 = (const float4*)(yr + ga);
                #pragma unroll
                for (int q = 0; q < 6; q++) {
                    float4 a = px4[q], bb = py4[q];
                    t0[q*4+0]=a.x; t0[q*4+1]=a.y; t0[q*4+2]=a.z; t0[q*4+3]=a.w;
                    t1[q*4+0]=bb.x; t1[q*4+1]=bb.y; t1[q*4+2]=bb.z; t1[q*4+3]=bb.w;
                }
                #pragma unroll
                for (int i = 0; i < 18; i++) { xw[i] = t0[3+i]; yw[i] = t1[3+i]; }
            } else {
                #pragma unroll
                for (int i = 0; i < 18; i++) {
                    int gc = gw + i;
                    bool ok = (gc >= 0 && gc < WW);
                    xw[i] = ok ? xr[gc] : 0.0f;
                    yw[i] = ok ? yr[gc] : 0.0f;
                }
            }
        } else {
            #pragma unroll
            for (int i = 0; i < 18; i++) { xw[i] = 0.0f; yw[i] = 0.0f; }
        }

        float aX[8], aY[8], aXX[8], aYY[8], aXY[8];
        #pragma unroll
        for (int j = 0; j < 8; j++) { aX[j]=0; aY[j]=0; aXX[j]=0; aYY[j]=0; aXY[j]=0; }
        #pragma unroll
        for (int i = 0; i < 18; i++) {
            float xv = xw[i], yv = yw[i];
            float xx = xv * xv, yy = yv * yv, xy = xv * yv;
            #pragma unroll
            for (int j = 0; j < 8; j++) {
                int k = i - j;                 // compile-time pruned
                if (k >= 0 && k < 11) {
                    float w = g[k];
                    aX[j]  += w * xv;
                    aY[j]  += w * yv;
                    aXX[j] += w * xx;
                    aYY[j] += w * yy;
                    aXY[j] += w * xy;
                }
            }
        }
        #pragma unroll
        for (int h = 0; h < 2; h++) {
            *(float4*)&hA[0][r][c0+4*h] = make_float4(aX[4*h], aX[4*h+1], aX[4*h+2], aX[4*h+3]);
            *(float4*)&hA[1][r][c0+4*h] = make_float4(aY[4*h], aY[4*h+1], aY[4*h+2], aY[4*h+3]);
            *(float4*)&hA[2][r][c0+4*h] = make_float4(aXX[4*h], aXX[4*h+1], aXX[4*h+2], aXX[4*h+3]);
            *(float4*)&hA[3][r][c0+4*h] = make_float4(aYY[4*h], aYY[4*h+1], aYY[4*h+2], aYY[4*h+3]);
            *(float4*)&hA[4][r][c0+4*h] = make_float4(aXY[4*h], aXY[4*h+1], aXY[4*h+2], aXY[4*h+3]);
        }
    }
    __syncthreads();

    // ---- Vertical pass: thread owns col c, rows r0..r0+3 (2-way max -> free) ----
    const int c  = tid & 31;
    const int r0 = (tid >> 5) * 4;
    float mu1[4], mu2[4], exx[4], eyy[4], exy[4];
    #pragma unroll
    for (int j = 0; j < 4; j++) { mu1[j]=0; mu2[j]=0; exx[j]=0; eyy[j]=0; exy[j]=0; }
    #pragma unroll
    for (int a = 0; a < 5; a++) {
        float v[14];
        #pragma unroll
        for (int i = 0; i < 14; i++) v[i] = hA[a][r0 + i][c];
        #pragma unroll
        for (int k = 0; k < 11; k++) {
            float w = g[k];
            #pragma unroll
            for (int j = 0; j < 4; j++) {
                float t = w * v[j + k];
                if (a == 0) mu1[j] += t;
                else if (a == 1) mu2[j] += t;
                else if (a == 2) exx[j] += t;
                else if (a == 3) eyy[j] += t;
                else exy[j] += t;
            }
        }
    }

    float ssim_s = 0.0f;
    const float C1v = 1e-4f, C2v = 9e-4f;
    #pragma unroll
    for (int j = 0; j < 4; j++) {
        float m1 = mu1[j], m2 = mu2[j];
        float m1s = m1 * m1, m2s = m2 * m2, m12 = m1 * m2;
        float s1 = exx[j] - m1s, s2 = eyy[j] - m2s, s12 = exy[j] - m12;
        float num = (2.0f * m12 + C1v) * (2.0f * s12 + C2v);
        float den = (m1s + m2s + C1v) * (s1 + s2 + C2v);
        ssim_s += num / den;
    }

    float ssim_b = block_reduce_256(ssim_s, rbuf);
    if (tid == 0)
        ssim_partials[(size_t)z * 64 + ty * 8 + tx] = ssim_b;
}

// One kernel for the whole MI path: 512 blocks = 64 batch x 8 eighths.
// Each block: u4 LDS histogram of its 24576 px + MSE partial -> ws. The LAST
// block per batch item (device-scope ticket) merges the 8 partials and writes
// all three outputs for that batch item.
__global__ __launch_bounds__(1024) void hist_mi_kernel(
    const float* __restrict__ x, const float* __restrict__ y,
    const float* __restrict__ ssim_partials,
    unsigned int* __restrict__ u4hist, float* __restrict__ mse_part,
    unsigned int* __restrict__ done_cnt,
    float* __restrict__ out)
{
    __shared__ unsigned int h32[8192];   // 8 u4 bins per word, 32 KB
    __shared__ unsigned int pyl[256];
    __shared__ float rbuf[16];
    __shared__ int is_last;

    const int z = blockIdx.x, t = threadIdx.x;   // b = z>>3, eighth = z&7
    const int b = z >> 3;
    const float invN = 1.0f / (float)NPB;

    uint4* h128 = (uint4*)h32;
    #pragma unroll
    for (int i = 0; i < 2; i++) h128[t + i * 1024] = make_uint4(0, 0, 0, 0);
    __syncthreads();

    const float4* x4 = (const float4*)x + (size_t)b * (NPB/4) + (size_t)(z & 7) * (EPX/4);
    const float4* y4 = (const float4*)y + (size_t)b * (NPB/4) + (size_t)(z & 7) * (EPX/4);
    float mse_s = 0.0f;
    for (int i = 0; i < 6; i++) {
        float4 xv = x4[t + i * 1024];
        float4 yv = y4[t + i * 1024];
        float xs[4] = {xv.x, xv.y, xv.z, xv.w};
        float ys[4] = {yv.x, yv.y, yv.z, yv.w};
        #pragma unroll
        for (int e = 0; e < 4; e++) {
            float xc = xs[e], yc = ys[e];
            float d = xc - yc;
            mse_s += d * d;
            int ix = (int)(((xc + 1.0f) * 0.5f) * 256.0f);
            int iy = (int)(((yc + 1.0f) * 0.5f) * 256.0f);
            ix = min(max(ix, 0), 255);
            iy = min(max(iy, 0), 255);
            int key = ix * NBINS + iy;
            atomicAdd(&h32[key >> 3], 1u << (4 * (key & 7)));
        }
    }
    __syncthreads();

    float mse_total = block_reduce_1024(mse_s, rbuf);
    if (t == 0) mse_part[z] = mse_total;

    // store u4 partial (coalesced)
    #pragma unroll
    for (int k = 0; k < 8; k++)
        u4hist[(size_t)z * 8192 + t + k * 1024] = h32[t + k * 1024];

    // ---- last-block election (device scope) ----
    __threadfence();
    if (t == 0) {
        unsigned int ticket = atomicAdd(&done_cnt[b], 1u);
        is_last = (ticket == 7u);
    }
    __syncthreads();
    if (!is_last) return;
    __threadfence();   // acquire: other blocks' partials/mse now visible

    // ---- merge 8 partials; MI = Hx + Hy - Hxy (Hxy separable per bin) ----
    if (t < 256) pyl[t] = 0;
    __syncthreads();

    float sxy = 0.0f, sx = 0.0f;
    for (int s = 0; s < 4; s++) {
        unsigned int s0a = 0, s1a = 0, s0b = 0, s1b = 0;
        #pragma unroll
        for (int p = 0; p < 8; p++) {
            const uint2* src = (const uint2*)(u4hist + (size_t)(b * 8 + p) * 8192 + s * 2048);
            uint2 v = src[t];
            s0a += v.x & 0x0F0F0F0Fu;  s1a += (v.x >> 4) & 0x0F0F0F0Fu;
            s0b += v.y & 0x0F0F0F0Fu;  s1b += (v.y >> 4) & 0x0F0F0F0Fu;
        }
        unsigned int cnt[16];     // bins 16t..16t+15 of slice s (complete counts)
        #pragma unroll
        for (int m = 0; m < 4; m++) {
            cnt[2*m]     = (s0a >> (8*m)) & 255u;
            cnt[2*m + 1] = (s1a >> (8*m)) & 255u;
            cnt[8 + 2*m]     = (s0b >> (8*m)) & 255u;
            cnt[8 + 2*m + 1] = (s1b >> (8*m)) & 255u;
        }
        unsigned int rowc = 0;
        #pragma unroll
        for (int k = 0; k < 16; k++) {
            unsigned int v = cnt[k];
            rowc += v;
            if (v) {
                float jp = (float)v * invN;
                sxy += jp * __log2f(jp);
            }
            atomicAdd(&pyl[(16 * t + k) & 255], v);
        }
        // row (ix) totals: 16 consecutive threads hold one row's 256 bins
        #pragma unroll
        for (int o = 8; o > 0; o >>= 1) rowc += __shfl_xor((int)rowc, o, 16);
        if ((t & 15) == 0 && rowc) {
            float px = (float)rowc * invN;
            sx += px * __log2f(px);
        }
    }
    __syncthreads();   // pyl complete

    float hxy = -block_reduce_1024(sxy, rbuf);
    float hx  = -block_reduce_1024(sx, rbuf);

    float ey = 0.0f;
    if (t < 256) {
        unsigned int pc = pyl[t];
        if (pc) {
            float py = (float)pc * invN;
            ey = -py * __log2f(py);
        }
    }
    float hy = block_reduce_1024(ey, rbuf);

    float ssim_total = block_reduce_1024(
        (t < 192) ? ssim_partials[(size_t)b * 192 + t] : 0.0f, rbuf);
    float mse_all = block_reduce_1024(
        (t < 8) ? mse_part[b * 8 + t] : 0.0f, rbuf);

    if (t == 0) {
        float mi = hx + hy - hxy;
        float norm = fminf(hx, hy);
        float m = (norm > 0.0f) ? (mi / norm) : 0.0f;
        m = fminf(fmaxf(m, 0.0f), 1.0f);
        out[b * 3 + 0] = m;
        out[b * 3 + 1] = ssim_total * invN;
        double mse = (double)mse_all * (1.0 / (4.0 * (double)NPB));
        out[b * 3 + 2] = (mse == 0.0) ? 2.5f : (float)(-10.0 * log10(mse) / 40.0);
    }
}

extern "C" void kernel_launch(void* const* d_in, const int* in_sizes, int n_in,
                              void* d_out, int out_size, void* d_ws, size_t ws_size,
                              hipStream_t stream) {
    const float* x   = (const float*)d_in[0];
    const float* y   = (const float*)d_in[1];
    const float* win = (const float*)d_in[2];
    float* out = (float*)d_out;

    // ws layout (no memset: done_cnt is zeroed by conv block (0,0,0); everything
    // else is fully written before it is read):
    //   done_cnt:      64 u32            256 B
    //   u4hist:        512*8192 u32      16 MB
    //   mse_part:      512 f32
    //   ssim_partials: 12288 f32
    char* p = (char*)d_ws;
    unsigned int* done_cnt = (unsigned int*)p;
    unsigned int* u4hist = (unsigned int*)(p + 256);
    size_t off = 256 + (size_t)BATCH * 8 * 8192 * sizeof(unsigned int);
    float* mse_part = (float*)(p + off);       off += BATCH * 8 * sizeof(float);
    float* ssim_partials = (float*)(p + off);

    dim3 grid(WW / TILE, HH / TILE, BATCH * CH);  // 8 x 8 x 192
    ssim_conv_kernel<<<grid, dim3(256), 0, stream>>>(x, y, win, ssim_partials, done_cnt);
    hist_mi_kernel<<<dim3(BATCH * 8), dim3(1024), 0, stream>>>(
        x, y, ssim_partials, u4hist, mse_part, done_cnt, out);
}

// Round 10
// 234.129 us; speedup vs baseline: 2.0644x; 2.0644x over previous
//
#include <hip/hip_runtime.h>
#include <cstdint>
#include <cstddef>

#define BATCH 64
#define CH 3
#define HH 256
#define WW 256
#define NBINS 256
#define TILE 32
#define HALO 5
#define HPAD 36                /* hA row stride */
#define NPB (CH*HH*WW)         /* 196608 elements per batch item */

// ws accumulator region (zeroed by conv's z==0,ty==0 blocks):
//   py_acc  u32[64*256]  @ 0        (65536 B)
//   hxy_acc f32[64]      @ 65536
//   hx_acc  f32[64]      @ 65792
//   mse_acc f32[64]      @ 66048
//   ssim_partials f32[12288] @ 66304  (written before read, not zeroed)
#define ZERO_WORDS 16576       /* 66304 / 4 */

__device__ __forceinline__ float block_reduce_256(float v, float* buf4) {
    #pragma unroll
    for (int o = 32; o > 0; o >>= 1) v += __shfl_down(v, o, 64);
    __syncthreads();
    int lane = threadIdx.x & 63;
    int wid  = threadIdx.x >> 6;
    if (lane == 0) buf4[wid] = v;
    __syncthreads();
    return buf4[0] + buf4[1] + buf4[2] + buf4[3];
}

__device__ __forceinline__ float block_reduce_1024(float v, float* buf16) {
    #pragma unroll
    for (int o = 32; o > 0; o >>= 1) v += __shfl_down(v, o, 64);
    __syncthreads();
    int lane = threadIdx.x & 63;
    int wid  = threadIdx.x >> 6;
    if (lane == 0) buf16[wid] = v;
    __syncthreads();
    float s = 0.0f;
    #pragma unroll
    for (int i = 0; i < 16; i++) s += buf16[i];
    return s;
}

// Separable 11x11 gaussian conv -> per-pixel SSIM (round-7 structure, 88 us).
// Blocks (tx, ty==0, z==0) also zero the accumulator region (replaces memset).
__global__ __launch_bounds__(256) void ssim_conv_kernel(
    const float* __restrict__ x, const float* __restrict__ y,
    const float* __restrict__ win,
    float* __restrict__ ssim_partials,
    unsigned int* __restrict__ zero_region)
{
    __shared__ float hA[5][42][HPAD];   // 30.2 KB
    __shared__ float g[16];
    __shared__ float rbuf[4];

    const int tid = threadIdx.x;
    const int tx = blockIdx.x, ty = blockIdx.y, z = blockIdx.z;  // z = b*3 + c
    const float* xi = x + (size_t)z * (HH * WW);
    const float* yi = y + (size_t)z * (HH * WW);

    if (z == 0 && ty == 0) {
        for (int j = tx * 256 + tid; j < ZERO_WORDS; j += 8 * 256)
            zero_region[j] = 0;
    }

    if (tid < 11) {
        // window = outer(g,g); recover g: g[i] = w2[5][i] / sqrt(w2[5][5])
        float g5 = sqrtf(win[5*11 + 5]);
        g[tid] = win[5*11 + tid] / g5;
    }
    __syncthreads();

    // ---- Horizontal pass: 42 rows x 4 strips of 8 -> 168 strips, one pass ----
    if (tid < 42 * 4) {
        int r = tid >> 2;
        int c0 = (tid & 3) * 8;
        int gr = ty * TILE - HALO + r;
        int gw = tx * TILE + c0 - HALO;       // gw % 8 == 3
        float xw[18], yw[18];
        bool rowok = (gr >= 0 && gr < HH);
        if (rowok) {
            const float* xr = xi + gr * WW;
            const float* yr = yi + gr * WW;
            int ga = gw - 3;                  // 16B-aligned
            if (ga >= 0 && ga + 24 <= WW) {
                float t0[24], t1[24];
                const float4* px4 = (const float4*)(xr + ga);
                const float4* py4 = (const float4*)(yr + ga);
                #pragma unroll
                for (int q = 0; q < 6; q++) {
                    float4 a = px4[q], bb = py4[q];
                    t0[q*4+0]=a.x; t0[q*4+1]=a.y; t0[q*4+2]=a.z; t0[q*4+3]=a.w;
                    t1[q*4+0]=bb.x; t1[q*4+1]=bb.y; t1[q*4+2]=bb.z; t1[q*4+3]=bb.w;
                }
                #pragma unroll
                for (int i = 0; i < 18; i++) { xw[i] = t0[3+i]; yw[i] = t1[3+i]; }
            } else {
                #pragma unroll
                for (int i = 0; i < 18; i++) {
                    int gc = gw + i;
                    bool ok = (gc >= 0 && gc < WW);
                    xw[i] = ok ? xr[gc] : 0.0f;
                    yw[i] = ok ? yr[gc] : 0.0f;
                }
            }
        } else {
            #pragma unroll
            for (int i = 0; i < 18; i++) { xw[i] = 0.0f; yw[i] = 0.0f; }
        }

        float aX[8], aY[8], aXX[8], aYY[8], aXY[8];
        #pragma unroll
        for (int j = 0; j < 8; j++) { aX[j]=0; aY[j]=0; aXX[j]=0; aYY[j]=0; aXY[j]=0; }
        #pragma unroll
        for (int i = 0; i < 18; i++) {
            float xv = xw[i], yv = yw[i];
            float xx = xv * xv, yy = yv * yv, xy = xv * yv;
            #pragma unroll
            for (int j = 0; j < 8; j++) {
                int k = i - j;                 // compile-time pruned
                if (k >= 0 && k < 11) {
                    float w = g[k];
                    aX[j]  += w * xv;
                    aY[j]  += w * yv;
                    aXX[j] += w * xx;
                    aYY[j] += w * yy;
                    aXY[j] += w * xy;
                }
            }
        }
        #pragma unroll
        for (int h = 0; h < 2; h++) {
            *(float4*)&hA[0][r][c0+4*h] = make_float4(aX[4*h], aX[4*h+1], aX[4*h+2], aX[4*h+3]);
            *(float4*)&hA[1][r][c0+4*h] = make_float4(aY[4*h], aY[4*h+1], aY[4*h+2], aY[4*h+3]);
            *(float4*)&hA[2][r][c0+4*h] = make_float4(aXX[4*h], aXX[4*h+1], aXX[4*h+2], aXX[4*h+3]);
            *(float4*)&hA[3][r][c0+4*h] = make_float4(aYY[4*h], aYY[4*h+1], aYY[4*h+2], aYY[4*h+3]);
            *(float4*)&hA[4][r][c0+4*h] = make_float4(aXY[4*h], aXY[4*h+1], aXY[4*h+2], aXY[4*h+3]);
        }
    }
    __syncthreads();

    // ---- Vertical pass: thread owns col c, rows r0..r0+3 ----
    const int c  = tid & 31;
    const int r0 = (tid >> 5) * 4;
    float mu1[4], mu2[4], exx[4], eyy[4], exy[4];
    #pragma unroll
    for (int j = 0; j < 4; j++) { mu1[j]=0; mu2[j]=0; exx[j]=0; eyy[j]=0; exy[j]=0; }
    #pragma unroll
    for (int a = 0; a < 5; a++) {
        float v[14];
        #pragma unroll
        for (int i = 0; i < 14; i++) v[i] = hA[a][r0 + i][c];
        #pragma unroll
        for (int k = 0; k < 11; k++) {
            float w = g[k];
            #pragma unroll
            for (int j = 0; j < 4; j++) {
                float t = w * v[j + k];
                if (a == 0) mu1[j] += t;
                else if (a == 1) mu2[j] += t;
                else if (a == 2) exx[j] += t;
                else if (a == 3) eyy[j] += t;
                else exy[j] += t;
            }
        }
    }

    float ssim_s = 0.0f;
    const float C1v = 1e-4f, C2v = 9e-4f;
    #pragma unroll
    for (int j = 0; j < 4; j++) {
        float m1 = mu1[j], m2 = mu2[j];
        float m1s = m1 * m1, m2s = m2 * m2, m12 = m1 * m2;
        float s1 = exx[j] - m1s, s2 = eyy[j] - m2s, s12 = exy[j] - m12;
        float num = (2.0f * m12 + C1v) * (2.0f * s12 + C2v);
        float den = (m1s + m2s + C1v) * (s1 + s2 + C2v);
        ssim_s += num / den;
    }

    float ssim_b = block_reduce_256(ssim_s, rbuf);
    if (tid == 0)
        ssim_partials[(size_t)z * 64 + ty * 8 + tx] = ssim_b;
}

// Value-partitioned histogram: 256 blocks = (b, ix-slice s). Block scans ALL of
// batch item b, bins only pixels with ix in [64s, 64s+64) -> its 64x256 u16 LDS
// histogram is COMPLETE. Hxy & Hx(slice rows) computed locally; py columns and
// scalars accumulated via device atomics (no fences, no partial round-trip).
// Slice-0 blocks also accumulate MSE (single writer per batch item).
__global__ __launch_bounds__(1024) void hist_slice_kernel(
    const float* __restrict__ x, const float* __restrict__ y,
    unsigned int* __restrict__ py_acc,
    float* __restrict__ hxy_acc, float* __restrict__ hx_acc,
    float* __restrict__ mse_acc)
{
    __shared__ unsigned int h32[8192];   // 16384 u16 bins (64 rows x 256 cols)
    __shared__ unsigned int pyl[256];
    __shared__ float rbuf[16];

    const int b = blockIdx.x >> 2, s = blockIdx.x & 3, t = threadIdx.x;
    const float invN = 1.0f / (float)NPB;

    uint4* h128 = (uint4*)h32;
    #pragma unroll
    for (int i = 0; i < 2; i++) h128[t + i * 1024] = make_uint4(0, 0, 0, 0);
    if (t < 256) pyl[t] = 0;
    __syncthreads();

    const float4* x4 = (const float4*)x + (size_t)b * (NPB / 4);
    const float4* y4 = (const float4*)y + (size_t)b * (NPB / 4);
    const int lo = s * 64, hi = lo + 64;
    float mse_s = 0.0f;
    for (int i = 0; i < 48; i++) {
        float4 xv = x4[t + i * 1024];
        float4 yv = y4[t + i * 1024];
        float xs[4] = {xv.x, xv.y, xv.z, xv.w};
        float ys[4] = {yv.x, yv.y, yv.z, yv.w};
        #pragma unroll
        for (int e = 0; e < 4; e++) {
            float xc = xs[e], yc = ys[e];
            if (s == 0) { float d = xc - yc; mse_s += d * d; }
            int ix = (int)(((xc + 1.0f) * 0.5f) * 256.0f);
            ix = min(max(ix, 0), 255);
            if (ix >= lo && ix < hi) {
                int iy = (int)(((yc + 1.0f) * 0.5f) * 256.0f);
                iy = min(max(iy, 0), 255);
                int kl = (ix - lo) * NBINS + iy;          // 14-bit local key
                atomicAdd(&h32[kl >> 1], (kl & 1) ? 65536u : 1u);
            }
        }
    }
    __syncthreads();

    // thread t owns bins [16t, 16t+16) = words [8t, 8t+8); row = t>>4 (complete)
    float sxy = 0.0f;
    unsigned int rowc = 0;
    #pragma unroll
    for (int wv = 0; wv < 8; wv++) {
        unsigned int v = h32[8 * t + wv];
        unsigned int c0 = v & 0xFFFFu, c1 = v >> 16;
        rowc += c0 + c1;
        if (c0) { float jp = (float)c0 * invN; sxy += jp * __log2f(jp); }
        if (c1) { float jp = (float)c1 * invN; sxy += jp * __log2f(jp); }
        int kl = 16 * t + 2 * wv;
        atomicAdd(&pyl[kl & 255], c0);
        atomicAdd(&pyl[(kl + 1) & 255], c1);
    }
    // row totals: 16 consecutive threads hold one row
    #pragma unroll
    for (int o = 8; o > 0; o >>= 1) rowc += __shfl_xor((int)rowc, o, 16);
    float sx = 0.0f;
    if ((t & 15) == 0 && rowc) {
        float px = (float)rowc * invN;
        sx = px * __log2f(px);
    }

    float sxy_blk = block_reduce_1024(sxy, rbuf);
    float sx_blk  = block_reduce_1024(sx, rbuf);
    float mse_blk = (s == 0) ? block_reduce_1024(mse_s, rbuf) : 0.0f;
    __syncthreads();   // pyl complete before re-read below

    if (t < 256) atomicAdd(&py_acc[b * 256 + t], pyl[t]);
    if (t == 0) {
        atomicAdd(&hxy_acc[b], sxy_blk);
        atomicAdd(&hx_acc[b],  sx_blk);
        if (s == 0) mse_acc[b] = mse_blk;   // single writer
    }
}

// Finalize: 64 blocks x 256 threads. Hy from py_acc; assemble MI/SSIM/PSNR.
__global__ __launch_bounds__(256) void finalize_kernel(
    const unsigned int* __restrict__ py_acc,
    const float* __restrict__ hxy_acc, const float* __restrict__ hx_acc,
    const float* __restrict__ mse_acc, const float* __restrict__ ssim_partials,
    float* __restrict__ out)
{
    __shared__ float rbuf[4];
    const int b = blockIdx.x, t = threadIdx.x;
    const float invN = 1.0f / (float)NPB;

    float ey = 0.0f;
    unsigned int pyc = py_acc[b * 256 + t];
    if (pyc) {
        float py = (float)pyc * invN;
        ey = -py * __log2f(py);
    }
    float hy = block_reduce_256(ey, rbuf);
    float ssim_total = block_reduce_256(
        (t < 192) ? ssim_partials[(size_t)b * 192 + t] : 0.0f, rbuf);

    if (t == 0) {
        float hx  = -hx_acc[b];
        float hxy = -hxy_acc[b];
        float mi = hx + hy - hxy;
        float norm = fminf(hx, hy);
        float m = (norm > 0.0f) ? (mi / norm) : 0.0f;
        m = fminf(fmaxf(m, 0.0f), 1.0f);
        out[b * 3 + 0] = m;
        out[b * 3 + 1] = ssim_total * invN;
        double mse = (double)mse_acc[b] * (1.0 / (4.0 * (double)NPB));
        out[b * 3 + 2] = (mse == 0.0) ? 2.5f : (float)(-10.0 * log10(mse) / 40.0);
    }
}

extern "C" void kernel_launch(void* const* d_in, const int* in_sizes, int n_in,
                              void* d_out, int out_size, void* d_ws, size_t ws_size,
                              hipStream_t stream) {
    const float* x   = (const float*)d_in[0];
    const float* y   = (const float*)d_in[1];
    const float* win = (const float*)d_in[2];
    float* out = (float*)d_out;

    char* p = (char*)d_ws;
    unsigned int* py_acc = (unsigned int*)p;                 // 65536 B
    float* hxy_acc = (float*)(p + 65536);                    // 256 B
    float* hx_acc  = (float*)(p + 65792);                    // 256 B
    float* mse_acc = (float*)(p + 66048);                    // 256 B
    float* ssim_partials = (float*)(p + 66304);              // 12288 f32

    dim3 grid(WW / TILE, HH / TILE, BATCH * CH);  // 8 x 8 x 192
    ssim_conv_kernel<<<grid, dim3(256), 0, stream>>>(
        x, y, win, ssim_partials, (unsigned int*)p);
    hist_slice_kernel<<<dim3(BATCH * 4), dim3(1024), 0, stream>>>(
        x, y, py_acc, hxy_acc, hx_acc, mse_acc);
    finalize_kernel<<<dim3(BATCH), dim3(256), 0, stream>>>(
        py_acc, hxy_acc, hx_acc, mse_acc, ssim_partials, out);
}

// Round 11
// 202.333 us; speedup vs baseline: 2.3888x; 1.1571x over previous
//
#include <hip/hip_runtime.h>
#include <cstdint>
#include <cstddef>

#define BATCH 64
#define CH 3
#define HH 256
#define WW 256
#define NBINS 256
#define TILE 32
#define HALO 5
#define HPAD 36                /* hA row stride (floats) */
#define NPB (CH*HH*WW)         /* 196608 elements per batch item */
#define EPX (NPB/8)            /* 24576 pixels per eighth-batch-item */
#define NHB 512                /* hist-role blocks (scheduled first) */

__device__ __forceinline__ float block_reduce_256(float v, float* buf4) {
    #pragma unroll
    for (int o = 32; o > 0; o >>= 1) v += __shfl_down(v, o, 64);
    __syncthreads();
    int lane = threadIdx.x & 63;
    int wid  = threadIdx.x >> 6;
    if (lane == 0) buf4[wid] = v;
    __syncthreads();
    return buf4[0] + buf4[1] + buf4[2] + buf4[3];
}

__device__ __forceinline__ float block_reduce_1024(float v, float* buf16) {
    #pragma unroll
    for (int o = 32; o > 0; o >>= 1) v += __shfl_down(v, o, 64);
    __syncthreads();
    int lane = threadIdx.x & 63;
    int wid  = threadIdx.x >> 6;
    if (lane == 0) buf16[wid] = v;
    __syncthreads();
    float s = 0.0f;
    #pragma unroll
    for (int i = 0; i < 16; i++) s += buf16[i];
    return s;
}

// Heterogeneous mega-kernel: bids [0,512) build u4 histogram partials + MSE
// (DS-atomic/memory-bound); bids [512, 12800) are 32x32 separable-conv SSIM
// tiles (VALU-bound). 32 KB LDS union -> 5 blocks/CU; roles co-scheduled.
__global__ __launch_bounds__(256) void mega_kernel(
    const float* __restrict__ x, const float* __restrict__ y,
    const float* __restrict__ win,
    float* __restrict__ ssim_partials,
    unsigned int* __restrict__ u4hist, float* __restrict__ mse_part)
{
    __shared__ __align__(16) unsigned char smem[32768];
    const int bid = blockIdx.x;
    const int tid = threadIdx.x;

    if (bid < NHB) {
        // ================= hist role =================
        unsigned int* h32 = (unsigned int*)smem;   // 8192 words, 8 u4 bins each
        uint4* h128 = (uint4*)h32;
        #pragma unroll
        for (int i = 0; i < 8; i++) h128[tid + i * 256] = make_uint4(0, 0, 0, 0);
        __syncthreads();

        const int b = bid >> 3, e = bid & 7;
        const float4* x4 = (const float4*)x + (size_t)b * (NPB/4) + (size_t)e * (EPX/4);
        const float4* y4 = (const float4*)y + (size_t)b * (NPB/4) + (size_t)e * (EPX/4);
        float mse_s = 0.0f;
        for (int i = 0; i < 24; i++) {
            float4 xv = x4[tid + i * 256];
            float4 yv = y4[tid + i * 256];
            float xs[4] = {xv.x, xv.y, xv.z, xv.w};
            float ys[4] = {yv.x, yv.y, yv.z, yv.w};
            #pragma unroll
            for (int q = 0; q < 4; q++) {
                float xc = xs[q], yc = ys[q];
                float d = xc - yc;
                mse_s += d * d;
                int ix = (int)(((xc + 1.0f) * 0.5f) * 256.0f);
                int iy = (int)(((yc + 1.0f) * 0.5f) * 256.0f);
                ix = min(max(ix, 0), 255);
                iy = min(max(iy, 0), 255);
                int key = ix * NBINS + iy;
                atomicAdd(&h32[key >> 3], 1u << (4 * (key & 7)));
            }
        }
        // per-wave MSE partial (no extra LDS needed)
        #pragma unroll
        for (int o = 32; o > 0; o >>= 1) mse_s += __shfl_down(mse_s, o, 64);
        if ((tid & 63) == 0) mse_part[bid * 4 + (tid >> 6)] = mse_s;
        __syncthreads();

        // store u4 partial (coalesced)
        #pragma unroll
        for (int k = 0; k < 32; k++)
            u4hist[(size_t)bid * 8192 + tid + k * 256] = h32[tid + k * 256];
        return;
    }

    // ================= conv role =================
    typedef float (*hA_t)[42][HPAD];
    hA_t hA = (hA_t)smem;                           // 5*42*36*4 = 30240 B
    float* g    = (float*)(smem + 30240);           // 64 B
    float* rbuf = (float*)(smem + 30304);           // 16 B

    const int cb = bid - NHB;
    const int tx = cb & 7, ty = (cb >> 3) & 7, z = cb >> 6;   // z = b*3 + c
    const float* xi = x + (size_t)z * (HH * WW);
    const float* yi = y + (size_t)z * (HH * WW);

    if (tid < 11) {
        // window = outer(g,g); recover g: g[i] = w2[5][i] / sqrt(w2[5][5])
        float g5 = sqrtf(win[5*11 + 5]);
        g[tid] = win[5*11 + tid] / g5;
    }
    __syncthreads();

    // ---- Horizontal pass: 42 rows x 4 strips of 8 -> 168 strips ----
    if (tid < 42 * 4) {
        int r = tid >> 2;
        int c0 = (tid & 3) * 8;
        int gr = ty * TILE - HALO + r;
        int gw = tx * TILE + c0 - HALO;       // gw % 8 == 3
        float xw[18], yw[18];
        bool rowok = (gr >= 0 && gr < HH);
        if (rowok) {
            const float* xr = xi + gr * WW;
            const float* yr = yi + gr * WW;
            int ga = gw - 3;                  // 16B-aligned
            if (ga >= 0 && ga + 24 <= WW) {
                float t0[24], t1[24];
                const float4* px4 = (const float4*)(xr + ga);
                const float4* py4 = (const float4*)(yr + ga);
                #pragma unroll
                for (int q = 0; q < 6; q++) {
                    float4 a = px4[q], bb = py4[q];
                    t0[q*4+0]=a.x; t0[q*4+1]=a.y; t0[q*4+2]=a.z; t0[q*4+3]=a.w;
                    t1[q*4+0]=bb.x; t1[q*4+1]=bb.y; t1[q*4+2]=bb.z; t1[q*4+3]=bb.w;
                }
                #pragma unroll
                for (int i = 0; i < 18; i++) { xw[i] = t0[3+i]; yw[i] = t1[3+i]; }
            } else {
                #pragma unroll
                for (int i = 0; i < 18; i++) {
                    int gc = gw + i;
                    bool ok = (gc >= 0 && gc < WW);
                    xw[i] = ok ? xr[gc] : 0.0f;
                    yw[i] = ok ? yr[gc] : 0.0f;
                }
            }
        } else {
            #pragma unroll
            for (int i = 0; i < 18; i++) { xw[i] = 0.0f; yw[i] = 0.0f; }
        }

        float aX[8], aY[8], aXX[8], aYY[8], aXY[8];
        #pragma unroll
        for (int j = 0; j < 8; j++) { aX[j]=0; aY[j]=0; aXX[j]=0; aYY[j]=0; aXY[j]=0; }
        #pragma unroll
        for (int i = 0; i < 18; i++) {
            float xv = xw[i], yv = yw[i];
            float xx = xv * xv, yy = yv * yv, xy = xv * yv;
            #pragma unroll
            for (int j = 0; j < 8; j++) {
                int k = i - j;                 // compile-time pruned
                if (k >= 0 && k < 11) {
                    float w = g[k];
                    aX[j]  += w * xv;
                    aY[j]  += w * yv;
                    aXX[j] += w * xx;
                    aYY[j] += w * yy;
                    aXY[j] += w * xy;
                }
            }
        }
        #pragma unroll
        for (int h = 0; h < 2; h++) {
            *(float4*)&hA[0][r][c0+4*h] = make_float4(aX[4*h], aX[4*h+1], aX[4*h+2], aX[4*h+3]);
            *(float4*)&hA[1][r][c0+4*h] = make_float4(aY[4*h], aY[4*h+1], aY[4*h+2], aY[4*h+3]);
            *(float4*)&hA[2][r][c0+4*h] = make_float4(aXX[4*h], aXX[4*h+1], aXX[4*h+2], aXX[4*h+3]);
            *(float4*)&hA[3][r][c0+4*h] = make_float4(aYY[4*h], aYY[4*h+1], aYY[4*h+2], aYY[4*h+3]);
            *(float4*)&hA[4][r][c0+4*h] = make_float4(aXY[4*h], aXY[4*h+1], aXY[4*h+2], aXY[4*h+3]);
        }
    }
    __syncthreads();

    // ---- Vertical pass: thread owns col c, rows r0..r0+3 ----
    const int c  = tid & 31;
    const int r0 = (tid >> 5) * 4;
    float mu1[4], mu2[4], exx[4], eyy[4], exy[4];
    #pragma unroll
    for (int j = 0; j < 4; j++) { mu1[j]=0; mu2[j]=0; exx[j]=0; eyy[j]=0; exy[j]=0; }
    #pragma unroll
    for (int a = 0; a < 5; a++) {
        float v[14];
        #pragma unroll
        for (int i = 0; i < 14; i++) v[i] = hA[a][r0 + i][c];
        #pragma unroll
        for (int k = 0; k < 11; k++) {
            float w = g[k];
            #pragma unroll
            for (int j = 0; j < 4; j++) {
                float t = w * v[j + k];
                if (a == 0) mu1[j] += t;
                else if (a == 1) mu2[j] += t;
                else if (a == 2) exx[j] += t;
                else if (a == 3) eyy[j] += t;
                else exy[j] += t;
            }
        }
    }

    float ssim_s = 0.0f;
    const float C1v = 1e-4f, C2v = 9e-4f;
    #pragma unroll
    for (int j = 0; j < 4; j++) {
        float m1 = mu1[j], m2 = mu2[j];
        float m1s = m1 * m1, m2s = m2 * m2, m12 = m1 * m2;
        float s1 = exx[j] - m1s, s2 = eyy[j] - m2s, s12 = exy[j] - m12;
        float num = (2.0f * m12 + C1v) * (2.0f * s12 + C2v);
        float den = (m1s + m2s + C1v) * (s1 + s2 + C2v);
        ssim_s += num / den;
    }

    float ssim_b = block_reduce_256(ssim_s, rbuf);
    if (tid == 0)
        ssim_partials[(size_t)z * 64 + ty * 8 + tx] = ssim_b;
}

// Merge+finalize: 64 blocks x 1024. Merge 8 u4 partials per batch item
// (nibble->byte SWAR, sums <= 120), MI = Hx + Hy - Hxy (Hxy separable per
// bin), Hy via LDS column marginal, then SSIM/MSE/PSNR assembly.
__global__ __launch_bounds__(1024) void merge_final_kernel(
    const unsigned int* __restrict__ u4hist,
    const float* __restrict__ mse_part,
    const float* __restrict__ ssim_partials,
    float* __restrict__ out)
{
    __shared__ unsigned int pyl[256];
    __shared__ float rbuf[16];
    const int b = blockIdx.x, t = threadIdx.x;
    const float invN = 1.0f / (float)NPB;

    if (t < 256) pyl[t] = 0;
    __syncthreads();

    float sxy = 0.0f, sx = 0.0f;
    for (int s = 0; s < 4; s++) {
        unsigned int s0a = 0, s1a = 0, s0b = 0, s1b = 0;
        #pragma unroll
        for (int p = 0; p < 8; p++) {
            const uint2* src = (const uint2*)(u4hist + (size_t)(b * 8 + p) * 8192 + s * 2048);
            uint2 v = src[t];
            s0a += v.x & 0x0F0F0F0Fu;  s1a += (v.x >> 4) & 0x0F0F0F0Fu;
            s0b += v.y & 0x0F0F0F0Fu;  s1b += (v.y >> 4) & 0x0F0F0F0Fu;
        }
        unsigned int cnt[16];     // bins 16t..16t+15 of slice s (complete counts)
        #pragma unroll
        for (int m = 0; m < 4; m++) {
            cnt[2*m]     = (s0a >> (8*m)) & 255u;
            cnt[2*m + 1] = (s1a >> (8*m)) & 255u;
            cnt[8 + 2*m]     = (s0b >> (8*m)) & 255u;
            cnt[8 + 2*m + 1] = (s1b >> (8*m)) & 255u;
        }
        unsigned int rowc = 0;
        #pragma unroll
        for (int k = 0; k < 16; k++) {
            unsigned int v = cnt[k];
            rowc += v;
            if (v) {
                float jp = (float)v * invN;
                sxy += jp * __log2f(jp);
            }
            atomicAdd(&pyl[(16 * t + k) & 255], v);
        }
        // row (ix) totals: 16 consecutive threads hold one row's 256 bins
        #pragma unroll
        for (int o = 8; o > 0; o >>= 1) rowc += __shfl_xor((int)rowc, o, 16);
        if ((t & 15) == 0 && rowc) {
            float px = (float)rowc * invN;
            sx += px * __log2f(px);
        }
    }
    __syncthreads();   // pyl complete

    float hxy = -block_reduce_1024(sxy, rbuf);
    float hx  = -block_reduce_1024(sx, rbuf);

    float ey = 0.0f;
    if (t < 256) {
        unsigned int pc = pyl[t];
        if (pc) {
            float py = (float)pc * invN;
            ey = -py * __log2f(py);
        }
    }
    float hy = block_reduce_1024(ey, rbuf);

    float ssim_total = block_reduce_1024(
        (t < 192) ? ssim_partials[(size_t)b * 192 + t] : 0.0f, rbuf);
    float mse_all = block_reduce_1024(
        (t < 32) ? mse_part[b * 32 + t] : 0.0f, rbuf);

    if (t == 0) {
        float mi = hx + hy - hxy;
        float norm = fminf(hx, hy);
        float m = (norm > 0.0f) ? (mi / norm) : 0.0f;
        m = fminf(fmaxf(m, 0.0f), 1.0f);
        out[b * 3 + 0] = m;
        out[b * 3 + 1] = ssim_total * invN;
        double mse = (double)mse_all * (1.0 / (4.0 * (double)NPB));
        out[b * 3 + 2] = (mse == 0.0) ? 2.5f : (float)(-10.0 * log10(mse) / 40.0);
    }
}

extern "C" void kernel_launch(void* const* d_in, const int* in_sizes, int n_in,
                              void* d_out, int out_size, void* d_ws, size_t ws_size,
                              hipStream_t stream) {
    const float* x   = (const float*)d_in[0];
    const float* y   = (const float*)d_in[1];
    const float* win = (const float*)d_in[2];
    float* out = (float*)d_out;

    // ws layout (everything fully written before read; no memset, no fences):
    //   u4hist:        512*8192 u32   16 MB
    //   mse_part:      2048 f32       8 KB   (4 per hist block)
    //   ssim_partials: 12288 f32      48 KB
    char* p = (char*)d_ws;
    unsigned int* u4hist = (unsigned int*)p;
    size_t off = (size_t)NHB * 8192 * sizeof(unsigned int);
    float* mse_part = (float*)(p + off);       off += (size_t)NHB * 4 * sizeof(float);
    float* ssim_partials = (float*)(p + off);

    mega_kernel<<<dim3(NHB + 8 * 8 * BATCH * CH), dim3(256), 0, stream>>>(
        x, y, win, ssim_partials, u4hist, mse_part);
    merge_final_kernel<<<dim3(BATCH), dim3(1024), 0, stream>>>(
        u4hist, mse_part, ssim_partials, out);
}

// Round 12
// 193.916 us; speedup vs baseline: 2.4925x; 1.0434x over previous
//
#include <hip/hip_runtime.h>
#include <cstdint>
#include <cstddef>

#define BATCH 64
#define CH 3
#define HH 256
#define WW 256
#define NBINS 256
#define TILE 32
#define HALO 5
#define HPAD 36                /* hA row stride (floats) */
#define NPB (CH*HH*WW)         /* 196608 elements per batch item */
#define EPX (NPB/8)            /* 24576 pixels per eighth-batch-item */
#define NHB 512                /* hist-role blocks (scheduled first) */

__device__ __forceinline__ float block_reduce_256(float v, float* buf4) {
    #pragma unroll
    for (int o = 32; o > 0; o >>= 1) v += __shfl_down(v, o, 64);
    __syncthreads();
    int lane = threadIdx.x & 63;
    int wid  = threadIdx.x >> 6;
    if (lane == 0) buf4[wid] = v;
    __syncthreads();
    return buf4[0] + buf4[1] + buf4[2] + buf4[3];
}

__device__ __forceinline__ float block_reduce_1024(float v, float* buf16) {
    #pragma unroll
    for (int o = 32; o > 0; o >>= 1) v += __shfl_down(v, o, 64);
    __syncthreads();
    int lane = threadIdx.x & 63;
    int wid  = threadIdx.x >> 6;
    if (lane == 0) buf16[wid] = v;
    __syncthreads();
    float s = 0.0f;
    #pragma unroll
    for (int i = 0; i < 16; i++) s += buf16[i];
    return s;
}

// Heterogeneous mega-kernel: bids [0,512) build u4 histogram partials + MSE;
// bids [512, 12800) are 32x32 separable-conv SSIM tiles. 32 KB LDS union.
__global__ __launch_bounds__(256) void mega_kernel(
    const float* __restrict__ x, const float* __restrict__ y,
    const float* __restrict__ win,
    float* __restrict__ ssim_partials,
    unsigned int* __restrict__ u4hist, float* __restrict__ mse_part)
{
    __shared__ __align__(16) unsigned char smem[32768];
    const int bid = blockIdx.x;
    const int tid = threadIdx.x;

    if (bid < NHB) {
        // ================= hist role =================
        unsigned int* h32 = (unsigned int*)smem;   // 8192 words, 8 u4 bins each
        uint4* h128 = (uint4*)h32;
        #pragma unroll
        for (int i = 0; i < 8; i++) h128[tid + i * 256] = make_uint4(0, 0, 0, 0);
        __syncthreads();

        const int b = bid >> 3, e = bid & 7;
        const float4* x4 = (const float4*)x + (size_t)b * (NPB/4) + (size_t)e * (EPX/4);
        const float4* y4 = (const float4*)y + (size_t)b * (NPB/4) + (size_t)e * (EPX/4);
        float mse_s = 0.0f;
        for (int i = 0; i < 24; i++) {
            float4 xv = x4[tid + i * 256];
            float4 yv = y4[tid + i * 256];
            float xs[4] = {xv.x, xv.y, xv.z, xv.w};
            float ys[4] = {yv.x, yv.y, yv.z, yv.w};
            #pragma unroll
            for (int q = 0; q < 4; q++) {
                float xc = xs[q], yc = ys[q];
                float d = xc - yc;
                mse_s += d * d;
                int ix = (int)(((xc + 1.0f) * 0.5f) * 256.0f);
                int iy = (int)(((yc + 1.0f) * 0.5f) * 256.0f);
                ix = min(max(ix, 0), 255);
                iy = min(max(iy, 0), 255);
                int key = ix * NBINS + iy;
                atomicAdd(&h32[key >> 3], 1u << (4 * (key & 7)));
            }
        }
        // per-wave MSE partial
        #pragma unroll
        for (int o = 32; o > 0; o >>= 1) mse_s += __shfl_down(mse_s, o, 64);
        if ((tid & 63) == 0) mse_part[bid * 4 + (tid >> 6)] = mse_s;
        __syncthreads();

        // store u4 partial (coalesced)
        #pragma unroll
        for (int k = 0; k < 32; k++)
            u4hist[(size_t)bid * 8192 + tid + k * 256] = h32[tid + k * 256];
        return;
    }

    // ================= conv role =================
    typedef float (*hA_t)[42][HPAD];
    hA_t hA = (hA_t)smem;                           // 30240 B
    float* g    = (float*)(smem + 30240);
    float* rbuf = (float*)(smem + 30304);

    const int cb = bid - NHB;
    const int tx = cb & 7, ty = (cb >> 3) & 7, z = cb >> 6;   // z = b*3 + c
    const float* xi = x + (size_t)z * (HH * WW);
    const float* yi = y + (size_t)z * (HH * WW);

    if (tid < 11) {
        float g5 = sqrtf(win[5*11 + 5]);
        g[tid] = win[5*11 + tid] / g5;
    }
    __syncthreads();

    // ---- Horizontal pass: 42 rows x 4 strips of 8 ----
    if (tid < 42 * 4) {
        int r = tid >> 2;
        int c0 = (tid & 3) * 8;
        int gr = ty * TILE - HALO + r;
        int gw = tx * TILE + c0 - HALO;       // gw % 8 == 3
        float xw[18], yw[18];
        bool rowok = (gr >= 0 && gr < HH);
        if (rowok) {
            const float* xr = xi + gr * WW;
            const float* yr = yi + gr * WW;
            int ga = gw - 3;
            if (ga >= 0 && ga + 24 <= WW) {
                float t0[24], t1[24];
                const float4* px4 = (const float4*)(xr + ga);
                const float4* py4 = (const float4*)(yr + ga);
                #pragma unroll
                for (int q = 0; q < 6; q++) {
                    float4 a = px4[q], bb = py4[q];
                    t0[q*4+0]=a.x; t0[q*4+1]=a.y; t0[q*4+2]=a.z; t0[q*4+3]=a.w;
                    t1[q*4+0]=bb.x; t1[q*4+1]=bb.y; t1[q*4+2]=bb.z; t1[q*4+3]=bb.w;
                }
                #pragma unroll
                for (int i = 0; i < 18; i++) { xw[i] = t0[3+i]; yw[i] = t1[3+i]; }
            } else {
                #pragma unroll
                for (int i = 0; i < 18; i++) {
                    int gc = gw + i;
                    bool ok = (gc >= 0 && gc < WW);
                    xw[i] = ok ? xr[gc] : 0.0f;
                    yw[i] = ok ? yr[gc] : 0.0f;
                }
            }
        } else {
            #pragma unroll
            for (int i = 0; i < 18; i++) { xw[i] = 0.0f; yw[i] = 0.0f; }
        }

        float aX[8], aY[8], aXX[8], aYY[8], aXY[8];
        #pragma unroll
        for (int j = 0; j < 8; j++) { aX[j]=0; aY[j]=0; aXX[j]=0; aYY[j]=0; aXY[j]=0; }
        #pragma unroll
        for (int i = 0; i < 18; i++) {
            float xv = xw[i], yv = yw[i];
            float xx = xv * xv, yy = yv * yv, xy = xv * yv;
            #pragma unroll
            for (int j = 0; j < 8; j++) {
                int k = i - j;
                if (k >= 0 && k < 11) {
                    float w = g[k];
                    aX[j]  += w * xv;
                    aY[j]  += w * yv;
                    aXX[j] += w * xx;
                    aYY[j] += w * yy;
                    aXY[j] += w * xy;
                }
            }
        }
        #pragma unroll
        for (int h = 0; h < 2; h++) {
            *(float4*)&hA[0][r][c0+4*h] = make_float4(aX[4*h], aX[4*h+1], aX[4*h+2], aX[4*h+3]);
            *(float4*)&hA[1][r][c0+4*h] = make_float4(aY[4*h], aY[4*h+1], aY[4*h+2], aY[4*h+3]);
            *(float4*)&hA[2][r][c0+4*h] = make_float4(aXX[4*h], aXX[4*h+1], aXX[4*h+2], aXX[4*h+3]);
            *(float4*)&hA[3][r][c0+4*h] = make_float4(aYY[4*h], aYY[4*h+1], aYY[4*h+2], aYY[4*h+3]);
            *(float4*)&hA[4][r][c0+4*h] = make_float4(aXY[4*h], aXY[4*h+1], aXY[4*h+2], aXY[4*h+3]);
        }
    }
    __syncthreads();

    // ---- Vertical pass ----
    const int c  = tid & 31;
    const int r0 = (tid >> 5) * 4;
    float mu1[4], mu2[4], exx[4], eyy[4], exy[4];
    #pragma unroll
    for (int j = 0; j < 4; j++) { mu1[j]=0; mu2[j]=0; exx[j]=0; eyy[j]=0; exy[j]=0; }
    #pragma unroll
    for (int a = 0; a < 5; a++) {
        float v[14];
        #pragma unroll
        for (int i = 0; i < 14; i++) v[i] = hA[a][r0 + i][c];
        #pragma unroll
        for (int k = 0; k < 11; k++) {
            float w = g[k];
            #pragma unroll
            for (int j = 0; j < 4; j++) {
                float t = w * v[j + k];
                if (a == 0) mu1[j] += t;
                else if (a == 1) mu2[j] += t;
                else if (a == 2) exx[j] += t;
                else if (a == 3) eyy[j] += t;
                else exy[j] += t;
            }
        }
    }

    float ssim_s = 0.0f;
    const float C1v = 1e-4f, C2v = 9e-4f;
    #pragma unroll
    for (int j = 0; j < 4; j++) {
        float m1 = mu1[j], m2 = mu2[j];
        float m1s = m1 * m1, m2s = m2 * m2, m12 = m1 * m2;
        float s1 = exx[j] - m1s, s2 = eyy[j] - m2s, s12 = exy[j] - m12;
        float num = (2.0f * m12 + C1v) * (2.0f * s12 + C2v);
        float den = (m1s + m2s + C1v) * (s1 + s2 + C2v);
        ssim_s += num / den;
    }

    float ssim_b = block_reduce_256(ssim_s, rbuf);
    if (tid == 0)
        ssim_partials[(size_t)z * 64 + ty * 8 + tx] = ssim_b;
}

// Merge: 256 blocks = (b, ix-slice s of 64 rows) x 1024. SWAR-merge the 8 u4
// partials' slice; Hxy & Hx terms local; column partials via xor-shuffle
// (NO LDS atomics); plain coalesced stores of per-slice partials.
__global__ __launch_bounds__(1024) void merge_kernel(
    const unsigned int* __restrict__ u4hist,
    unsigned int* __restrict__ py_part,
    float* __restrict__ sxy_part, float* __restrict__ sx_part)
{
    __shared__ unsigned int colw[16][256];   // 16 KB per-wave column partials
    __shared__ float rbuf[16];
    const int b = blockIdx.x >> 2, s = blockIdx.x & 3, t = threadIdx.x;
    const float invN = 1.0f / (float)NPB;

    // merge 8 partials: thread t owns bins 16t..16t+15 of slice s (complete)
    unsigned int s0a = 0, s1a = 0, s0b = 0, s1b = 0;
    #pragma unroll
    for (int p = 0; p < 8; p++) {
        const uint2* src = (const uint2*)(u4hist + (size_t)(b * 8 + p) * 8192 + s * 2048);
        uint2 v = src[t];
        s0a += v.x & 0x0F0F0F0Fu;  s1a += (v.x >> 4) & 0x0F0F0F0Fu;
        s0b += v.y & 0x0F0F0F0Fu;  s1b += (v.y >> 4) & 0x0F0F0F0Fu;
    }
    unsigned int cnt[16];
    #pragma unroll
    for (int m = 0; m < 4; m++) {
        cnt[2*m]     = (s0a >> (8*m)) & 255u;
        cnt[2*m + 1] = (s1a >> (8*m)) & 255u;
        cnt[8 + 2*m]     = (s0b >> (8*m)) & 255u;
        cnt[8 + 2*m + 1] = (s1b >> (8*m)) & 255u;
    }

    // Hxy terms + row count (row = t>>4 of slice; cols 16*(t&15)+k)
    float sxy = 0.0f;
    unsigned int rowc = 0;
    #pragma unroll
    for (int k = 0; k < 16; k++) {
        unsigned int v = cnt[k];
        rowc += v;
        if (v) {
            float jp = (float)v * invN;
            sxy += jp * __log2f(jp);
        }
    }
    #pragma unroll
    for (int o = 8; o > 0; o >>= 1) rowc += __shfl_xor((int)rowc, o, 16);
    float sx = 0.0f;
    if ((t & 15) == 0 && rowc) {
        float px = (float)rowc * invN;
        sx = px * __log2f(px);
    }

    // column partials: lanes l, l^16, l^32 own the same 16 cols (4 rows/wave)
    #pragma unroll
    for (int k = 0; k < 16; k++) {
        cnt[k] += __shfl_xor((int)cnt[k], 16, 64);
        cnt[k] += __shfl_xor((int)cnt[k], 32, 64);
    }
    const int w = t >> 6, l = t & 63;
    if (l < 16) {
        #pragma unroll
        for (int j = 0; j < 4; j++)
            *(uint4*)&colw[w][16 * l + 4 * j] =
                make_uint4(cnt[4*j], cnt[4*j+1], cnt[4*j+2], cnt[4*j+3]);
    }

    float sxy_blk = block_reduce_1024(sxy, rbuf);   // includes __syncthreads
    float sx_blk  = block_reduce_1024(sx, rbuf);

    if (t < 256) {
        unsigned int pc = 0;
        #pragma unroll
        for (int ww = 0; ww < 16; ww++) pc += colw[ww][t];
        py_part[(size_t)blockIdx.x * 256 + t] = pc;
    }
    if (t == 0) {
        sxy_part[blockIdx.x] = sxy_blk;
        sx_part[blockIdx.x]  = sx_blk;
    }
}

// Finalize: 64 blocks x 256. Sum 4 slice partials; Hy; assemble outputs.
__global__ __launch_bounds__(256) void finalize_kernel(
    const unsigned int* __restrict__ py_part,
    const float* __restrict__ sxy_part, const float* __restrict__ sx_part,
    const float* __restrict__ mse_part, const float* __restrict__ ssim_partials,
    float* __restrict__ out)
{
    __shared__ float rbuf[4];
    const int b = blockIdx.x, t = threadIdx.x;
    const float invN = 1.0f / (float)NPB;

    unsigned int pyc = py_part[(size_t)(b * 4 + 0) * 256 + t]
                     + py_part[(size_t)(b * 4 + 1) * 256 + t]
                     + py_part[(size_t)(b * 4 + 2) * 256 + t]
                     + py_part[(size_t)(b * 4 + 3) * 256 + t];
    float ey = 0.0f;
    if (pyc) {
        float py = (float)pyc * invN;
        ey = -py * __log2f(py);
    }
    float hy = block_reduce_256(ey, rbuf);
    float ssim_total = block_reduce_256(
        (t < 192) ? ssim_partials[(size_t)b * 192 + t] : 0.0f, rbuf);
    float mse_all = block_reduce_256(
        (t < 32) ? mse_part[b * 32 + t] : 0.0f, rbuf);

    if (t == 0) {
        float hxy = -(sxy_part[b*4] + sxy_part[b*4+1] + sxy_part[b*4+2] + sxy_part[b*4+3]);
        float hx  = -(sx_part[b*4] + sx_part[b*4+1] + sx_part[b*4+2] + sx_part[b*4+3]);
        float mi = hx + hy - hxy;
        float norm = fminf(hx, hy);
        float m = (norm > 0.0f) ? (mi / norm) : 0.0f;
        m = fminf(fmaxf(m, 0.0f), 1.0f);
        out[b * 3 + 0] = m;
        out[b * 3 + 1] = ssim_total * invN;
        double mse = (double)mse_all * (1.0 / (4.0 * (double)NPB));
        out[b * 3 + 2] = (mse == 0.0) ? 2.5f : (float)(-10.0 * log10(mse) / 40.0);
    }
}

extern "C" void kernel_launch(void* const* d_in, const int* in_sizes, int n_in,
                              void* d_out, int out_size, void* d_ws, size_t ws_size,
                              hipStream_t stream) {
    const float* x   = (const float*)d_in[0];
    const float* y   = (const float*)d_in[1];
    const float* win = (const float*)d_in[2];
    float* out = (float*)d_out;

    // ws layout (everything fully written before read; no memset, no fences):
    //   u4hist:        512*8192 u32   16 MB
    //   mse_part:      2048 f32
    //   ssim_partials: 12288 f32
    //   py_part:       256*256 u32    256 KB
    //   sxy_part:      256 f32
    //   sx_part:       256 f32
    char* p = (char*)d_ws;
    unsigned int* u4hist = (unsigned int*)p;
    size_t off = (size_t)NHB * 8192 * sizeof(unsigned int);
    float* mse_part = (float*)(p + off);        off += (size_t)NHB * 4 * sizeof(float);
    float* ssim_partials = (float*)(p + off);   off += (size_t)BATCH * 192 * sizeof(float);
    unsigned int* py_part = (unsigned int*)(p + off);  off += (size_t)256 * 256 * sizeof(unsigned int);
    float* sxy_part = (float*)(p + off);        off += 256 * sizeof(float);
    float* sx_part  = (float*)(p + off);

    mega_kernel<<<dim3(NHB + 8 * 8 * BATCH * CH), dim3(256), 0, stream>>>(
        x, y, win, ssim_partials, u4hist, mse_part);
    merge_kernel<<<dim3(BATCH * 4), dim3(1024), 0, stream>>>(
        u4hist, py_part, sxy_part, sx_part);
    finalize_kernel<<<dim3(BATCH), dim3(256), 0, stream>>>(
        py_part, sxy_part, sx_part, mse_part, ssim_partials, out);
}